// Round 2
// baseline (182.659 us; speedup 1.0000x reference)
//
#include <hip/hip_runtime.h>

// ShiftWise conv: lora1 = 15x3 conv, lora2 = 3x15 conv, small = 3x3 conv (i=2),
// each BN'd with batch stats, + rep_x residual; ghost channels copied through.
// Pass1 computes per-channel sum/sumsq of the three conv outputs (recompute
// strategy), reduce kernel folds stats into (A1,A2,A3,K), pass2 recomputes the
// convs and writes y = A1*l1 + A2*l2 + A3*s + K + x. All f32.

#define LSTRIDE 76
#define LROWS 70
#define LDS_FLOATS (LROWS * LSTRIDE)
// LDS index: row = h + 6 (h in [-6,63]), col = w + 10 (w in [-10,65])

__device__ __forceinline__ void load_tile(float* tile, const float* __restrict__ src, int tid) {
  #pragma unroll 1
  for (int g = tid; g < LDS_FLOATS / 4; g += 256)
    reinterpret_cast<float4*>(tile)[g] = float4{0.f, 0.f, 0.f, 0.f};
  __syncthreads();
  #pragma unroll 1
  for (int g = tid; g < 784; g += 256) {
    float4 v = reinterpret_cast<const float4*>(src)[g];
    int r = g / 14, c4 = g - r * 14;
    float* p = &tile[(r + 6) * LSTRIDE + 10 + 4 * c4];
    reinterpret_cast<float2*>(p)[0] = float2{v.x, v.y};   // interior is 8B-aligned only
    reinterpret_cast<float2*>(p)[1] = float2{v.z, v.w};
  }
  __syncthreads();
}

// lora1: 15x3 conv. Also captures rep_x values (xc) for free from the row data.
__device__ __forceinline__ void conv_lora1(
    const float* tile, const float* wv, int h0, int w0,
    float (&a1)[4][4], float (&xc)[4][4]) {
  #pragma unroll
  for (int rr = 0; rr < 18; ++rr) {              // X row = h0 - 6 + rr
    const float* rp = &tile[(h0 + rr) * LSTRIDE + w0 + 8];  // cols w0-2 .. w0+5
    const float4 qa = *reinterpret_cast<const float4*>(rp);
    const float4 qb = *reinterpret_cast<const float4*>(rp + 4);
    const float xr[8] = {qa.x, qa.y, qa.z, qa.w, qb.x, qb.y, qb.z, qb.w};
    if (rr >= 6 && rr < 10) {                    // X row == h0 + (rr-6): residual values
      #pragma unroll
      for (int dw = 0; dw < 4; ++dw) xc[rr - 6][dw] = xr[dw + 2];
    }
    #pragma unroll
    for (int dh = 0; dh < 4; ++dh) {
      const int t = rr - dh;                     // vertical tap, = 3i+kh
      if (t >= 0 && t < 15) {
        #pragma unroll
        for (int kw = 0; kw < 3; ++kw) {
          const float wgt = wv[3 * t + kw];      // (t/3)*9 + (t%3)*3 + kw == 3t+kw
          #pragma unroll
          for (int dw = 0; dw < 4; ++dw)
            a1[dh][dw] = fmaf(xr[dw + kw + 1], wgt, a1[dh][dw]);
        }
      }
    }
  }
}

// lora2: 3x15 conv, small: 3x3 conv — same rows (h0-1 .. h0+4), fused.
__device__ __forceinline__ void conv_l2s(
    const float* tile, const float* wv, int h0, int w0,
    float (&a2)[4][4], float (&a3)[4][4]) {
  #pragma unroll
  for (int rr = 0; rr < 6; ++rr) {               // X row = h0 - 1 + rr; rr = dh + kh
    const float* rp = &tile[(h0 + 5 + rr) * LSTRIDE + w0 + 4];  // cols w0-6 ..
    #pragma unroll
    for (int g = 0; g < 5; ++g) {
      const float4 q = reinterpret_cast<const float4*>(rp)[g];
      const float xq[4] = {q.x, q.y, q.z, q.w};
      #pragma unroll
      for (int v = 0; v < 4; ++v) {
        const int vv = 4 * g + v;                // col = w0 - 6 + vv
        #pragma unroll
        for (int dh = 0; dh < 4; ++dh) {
          const int kh = rr - dh;
          if (kh >= 0 && kh < 3) {
            #pragma unroll
            for (int dw = 0; dw < 4; ++dw) {
              const int t = vv - dw;             // horizontal tap = 3i+kw
              if (t >= 0 && t < 15)
                a2[dh][dw] = fmaf(xq[v], wv[(t / 3) * 9 + kh * 3 + (t % 3)], a2[dh][dw]);
              const int kw2 = vv - 5 - dw;       // small: col = w0+dw-1+kw2
              if (kw2 >= 0 && kw2 < 3)
                a3[dh][dw] = fmaf(xq[v], wv[18 + kh * 3 + kw2], a3[dh][dw]);
            }
          }
        }
      }
    }
  }
}

extern "C" __global__ void sw_prep(const float* __restrict__ w1, const float* __restrict__ w2,
                                   float* __restrict__ wsum) {
  int i = blockIdx.x * 256 + threadIdx.x;
  if (i < 8820) wsum[i] = w1[i] + w2[i];
}

extern "C" __global__ __launch_bounds__(256) void sw_pass1(
    const float* __restrict__ in, const int* __restrict__ rep_idx,
    const float* __restrict__ wsum, float* __restrict__ partial) {
  __shared__ float tile[LDS_FLOATS];
  __shared__ float red[4][6];
  const int bid = blockIdx.x;
  const int c = bid >> 5, b = bid & 31;
  const int tid = threadIdx.x;
  const int src_c = rep_idx[c];
  load_tile(tile, in + (size_t)(b * 256 + src_c) * 3136, tid);
  float wv[45];
  {
    const float* wp = wsum + c * 45;
    #pragma unroll
    for (int j = 0; j < 45; ++j) wv[j] = wp[j];
  }
  float s1 = 0, q1 = 0, s2 = 0, q2 = 0, s3 = 0, q3 = 0;
  if (tid < 196) {
    const int th = tid / 14, tw = tid - th * 14;
    const int h0 = th * 4, w0 = tw * 4;
    {
      float a1[4][4] = {}, xc[4][4];
      conv_lora1(tile, wv, h0, w0, a1, xc);
      #pragma unroll
      for (int dh = 0; dh < 4; ++dh)
        #pragma unroll
        for (int dw = 0; dw < 4; ++dw) { float v = a1[dh][dw]; s1 += v; q1 = fmaf(v, v, q1); }
    }
    {
      float a2[4][4] = {}, a3[4][4] = {};
      conv_l2s(tile, wv, h0, w0, a2, a3);
      #pragma unroll
      for (int dh = 0; dh < 4; ++dh)
        #pragma unroll
        for (int dw = 0; dw < 4; ++dw) {
          float v = a2[dh][dw]; s2 += v; q2 = fmaf(v, v, q2);
          float u = a3[dh][dw]; s3 += u; q3 = fmaf(u, u, q3);
        }
    }
  }
  #pragma unroll
  for (int off = 32; off > 0; off >>= 1) {
    s1 += __shfl_down(s1, off); q1 += __shfl_down(q1, off);
    s2 += __shfl_down(s2, off); q2 += __shfl_down(q2, off);
    s3 += __shfl_down(s3, off); q3 += __shfl_down(q3, off);
  }
  const int lane = tid & 63, wid = tid >> 6;
  if (lane == 0) {
    red[wid][0] = s1; red[wid][1] = q1; red[wid][2] = s2;
    red[wid][3] = q2; red[wid][4] = s3; red[wid][5] = q3;
  }
  __syncthreads();
  if (tid < 6)
    partial[bid * 6 + tid] = red[0][tid] + red[1][tid] + red[2][tid] + red[3][tid];
}

extern "C" __global__ void sw_reduce(
    const float* __restrict__ partial,
    const float* __restrict__ g1, const float* __restrict__ b1,
    const float* __restrict__ g2, const float* __restrict__ b2,
    const float* __restrict__ g3, const float* __restrict__ b3,
    float* __restrict__ stats2) {
  const int c = blockIdx.x;
  const int tid = threadIdx.x;
  __shared__ float sm[6];
  if (tid < 6) {
    float s = 0;
    for (int b = 0; b < 32; ++b) s += partial[(c * 32 + b) * 6 + tid];
    sm[tid] = s;
  }
  __syncthreads();
  if (tid == 0) {
    const float N = 100352.f;
    float m1 = sm[0] / N, v1 = sm[1] / N - m1 * m1;
    float m2 = sm[2] / N, v2 = sm[3] / N - m2 * m2;
    float m3 = sm[4] / N, v3 = sm[5] / N - m3 * m3;
    float A1 = g1[c] * rsqrtf(v1 + 1e-5f);
    float A2 = g2[c] * rsqrtf(v2 + 1e-5f);
    float A3 = g3[c] * rsqrtf(v3 + 1e-5f);
    float K = b1[c] + b2[c] + b3[c] - m1 * A1 - m2 * A2 - m3 * A3;
    stats2[c * 4 + 0] = A1; stats2[c * 4 + 1] = A2;
    stats2[c * 4 + 2] = A3; stats2[c * 4 + 3] = K;
  }
}

extern "C" __global__ __launch_bounds__(256) void sw_pass2(
    const float* __restrict__ in, const int* __restrict__ rep_idx,
    const int* __restrict__ ghost_idx, const float* __restrict__ wsum,
    const float* __restrict__ stats2, float* __restrict__ out) {
  const int bid = blockIdx.x;
  const int tid = threadIdx.x;
  if (bid >= 6272) {                      // ghost channel copy
    const int g2 = bid - 6272;
    const int j = g2 >> 5, b = g2 & 31;
    const int src_c = ghost_idx[j];
    const float4* s = reinterpret_cast<const float4*>(in + (size_t)(b * 256 + src_c) * 3136);
    float4* d = reinterpret_cast<float4*>(out + ((size_t)(b * 256) + 196 + j) * 3136);
    #pragma unroll 1
    for (int g = tid; g < 784; g += 256) d[g] = s[g];
    return;
  }
  __shared__ float tile[LDS_FLOATS];
  const int c = bid >> 5, b = bid & 31;
  const int src_c = rep_idx[c];
  load_tile(tile, in + (size_t)(b * 256 + src_c) * 3136, tid);
  float wv[45];
  {
    const float* wp = wsum + c * 45;
    #pragma unroll
    for (int j = 0; j < 45; ++j) wv[j] = wp[j];
  }
  const float A1 = stats2[c * 4 + 0], A2 = stats2[c * 4 + 1];
  const float A3 = stats2[c * 4 + 2], K = stats2[c * 4 + 3];
  if (tid < 196) {
    const int th = tid / 14, tw = tid - th * 14;
    const int h0 = th * 4, w0 = tw * 4;
    float y[4][4];
    {
      float a1[4][4] = {}, xc[4][4];
      conv_lora1(tile, wv, h0, w0, a1, xc);
      #pragma unroll
      for (int dh = 0; dh < 4; ++dh)
        #pragma unroll
        for (int dw = 0; dw < 4; ++dw)
          y[dh][dw] = fmaf(A1, a1[dh][dw], K + xc[dh][dw]);
    }
    {
      float a2[4][4] = {}, a3[4][4] = {};
      conv_l2s(tile, wv, h0, w0, a2, a3);
      #pragma unroll
      for (int dh = 0; dh < 4; ++dh)
        #pragma unroll
        for (int dw = 0; dw < 4; ++dw) {
          y[dh][dw] = fmaf(A2, a2[dh][dw], y[dh][dw]);
          y[dh][dw] = fmaf(A3, a3[dh][dw], y[dh][dw]);
        }
    }
    float* op = out + ((size_t)(b * 256) + c) * 3136;
    #pragma unroll
    for (int dh = 0; dh < 4; ++dh) {
      float4 o{y[dh][0], y[dh][1], y[dh][2], y[dh][3]};
      *reinterpret_cast<float4*>(op + (h0 + dh) * 56 + w0) = o;
    }
  }
}

extern "C" void kernel_launch(void* const* d_in, const int* in_sizes, int n_in,
                              void* d_out, int out_size, void* d_ws, size_t ws_size,
                              hipStream_t stream) {
  const float* in  = (const float*)d_in[0];
  const float* w1  = (const float*)d_in[1];
  const float* w2  = (const float*)d_in[2];
  const float* g1  = (const float*)d_in[3];
  const float* b1  = (const float*)d_in[4];
  const float* g2  = (const float*)d_in[5];
  const float* b2  = (const float*)d_in[6];
  const float* g3  = (const float*)d_in[7];
  const float* b3  = (const float*)d_in[8];
  const int* ghost_idx = (const int*)d_in[9];
  const int* rep_idx   = (const int*)d_in[10];
  float* out = (float*)d_out;
  float* ws  = (float*)d_ws;

  float* wsum    = ws;          // 8820 floats
  float* stats2  = ws + 8832;   // 784 floats
  float* partial = ws + 9728;   // 37632 floats

  sw_prep<<<35, 256, 0, stream>>>(w1, w2, wsum);
  sw_pass1<<<6272, 256, 0, stream>>>(in, rep_idx, wsum, partial);
  sw_reduce<<<196, 64, 0, stream>>>(partial, g1, b1, g2, b2, g3, b3, stats2);
  sw_pass2<<<8192, 256, 0, stream>>>(in, rep_idx, ghost_idx, wsum, stats2, out);
}

// Round 4
// 170.399 us; speedup vs baseline: 1.0719x; 1.0719x over previous
//
#include <hip/hip_runtime.h>

// ShiftWise conv, register-sliding-window version (no LDS tiles).
// lora1 = 15x3 conv, lora2 = 3x15 conv, small = 3x3 conv (i=2), each BN'd
// with batch stats, + rep_x residual; ghost channels copied through.
// Pass1: per-(c,rowblock) sum/sumsq of the three conv outputs.
// Reduce: fold stats into (A1,A2,A3,K). Pass2: recompute convs, write
// y = A1*l1 + A2*l2 + A3*s + K + x.
//
// Thread layout: block = 448 threads = 32 batches x 14 column strips; each
// thread owns an 8-row x 4-col output strip of one (b, c) image and walks
// input rows with a 20-float register window (global loads, L1-resident).
// Channel c is uniform per block -> weights in SGPRs. XCD swizzle keeps a
// channel's 7 rowblocks on one XCD (consecutive bids round-robin XCDs).

#define B_    32
#define CIN   256
#define REPN  196
#define HW    56
#define IMG   3136
#define NTOT  (B_ * CIN * IMG)
#define NCONVBLK 1400   // 25 groups of 56 = (8 channels x 7 rowblocks)
#define NGHOSTBLK 1920  // 60 ghost channels * 32 batches

template <bool PASS2>
__launch_bounds__(448)
__global__ void sw_conv(const float* __restrict__ in, const int* __restrict__ rep_idx,
                        const int* __restrict__ ghost_idx, const float* __restrict__ wsum,
                        const float* __restrict__ stats2, float* __restrict__ partial,
                        float* __restrict__ out) {
  const int bid = blockIdx.x;
  const int tid = threadIdx.x;

  if (PASS2 && bid >= NCONVBLK) {  // ghost channel copy
    const int g = bid - NCONVBLK;
    const int j = g >> 5, b = g & 31;
    const int src_c = ghost_idx[j];
    const float4* s = reinterpret_cast<const float4*>(in + (size_t)(b * CIN + src_c) * IMG);
    float4* d = reinterpret_cast<float4*>(out + ((size_t)(b * CIN) + REPN + j) * IMG);
    #pragma unroll 1
    for (int i = tid; i < 784; i += 448) d[i] = s[i];
    return;
  }

  // XCD swizzle: channel c's 7 rowblocks sit at bids {56k + 8*rb + x}, all
  // congruent mod 8 -> same XCD -> shared L2 for the overlapping row reads.
  const int c = (bid / 56) * 8 + (bid & 7);
  const int rb = (bid % 56) >> 3;
  if (c >= REPN) return;
  const int h0 = rb * 8;

  const int b = tid / 14;        // 0..31
  const int tw = tid - b * 14;   // 0..13
  const int w0 = tw * 4;
  const int src_c = rep_idx[c];
  const int ibase = (b * CIN + src_c) * IMG;

  float wv[45];  // uniform per block -> SGPRs
  #pragma unroll
  for (int j = 0; j < 45; ++j) wv[j] = wsum[c * 45 + j];

  float A1 = 0.f, A2 = 0.f, A3 = 0.f, K_ = 0.f;
  if (PASS2) {
    A1 = stats2[c * 4 + 0]; A2 = stats2[c * 4 + 1];
    A3 = stats2[c * 4 + 2]; K_ = stats2[c * 4 + 3];
  }

  // window validity masks (window cols = w0-8+e, e in [0,20))
  const float ma = (tw >= 2) ? 1.f : 0.f;   // e 0..3   (col < 0)
  const float mb = (tw >= 1) ? 1.f : 0.f;   // e 4..7
  const float mc = (tw <= 12) ? 1.f : 0.f;  // e 12..15 (col >= 56)
  const float md = (tw <= 11) ? 1.f : 0.f;  // e 16..19

  float acc1[8][4] = {};
  float acc2[3][4] = {};
  float acc3[3][4] = {};
  float stash[7][4];  // PASS2 only: A2*l2 + A3*s held until lora1 completes
  float s1 = 0, q1 = 0, s2 = 0, q2 = 0, s3 = 0, q3 = 0;

  #pragma unroll
  for (int s = 0; s < 22; ++s) {
    const int r = h0 - 6 + s;
    if (r >= 0 && r < HW) {
      float win[20];
      {
        const int base = ibase + r * HW + w0 - 8;
        #pragma unroll
        for (int g = 0; g < 5; ++g) {
          int idx = base + 4 * g;
          idx = idx < 0 ? 0 : idx;                    // clamp: OOB lanes are masked anyway
          idx = idx > (NTOT - 4) ? (NTOT - 4) : idx;
          const float4 v = *reinterpret_cast<const float4*>(in + idx);
          win[4 * g + 0] = v.x; win[4 * g + 1] = v.y;
          win[4 * g + 2] = v.z; win[4 * g + 3] = v.w;
        }
      }
      #pragma unroll
      for (int e = 0; e < 4; ++e) win[e] *= ma;
      #pragma unroll
      for (int e = 4; e < 8; ++e) win[e] *= mb;
      #pragma unroll
      for (int e = 12; e < 16; ++e) win[e] *= mc;
      #pragma unroll
      for (int e = 16; e < 20; ++e) win[e] *= md;

      // lora1 (15x3): vertical tap t = s - lr, x col = w+kw-1 -> e = dw+kw+7
      #pragma unroll
      for (int lr = 0; lr < 8; ++lr) {
        const int t = s - lr;
        if (t >= 0 && t < 15) {
          #pragma unroll
          for (int kw = 0; kw < 3; ++kw) {
            const float wgt = wv[3 * t + kw];
            #pragma unroll
            for (int dw = 0; dw < 4; ++dw)
              acc1[lr][dw] = fmaf(win[dw + kw + 7], wgt, acc1[lr][dw]);
          }
        }
      }
      // lora2 (3x15) + small (3x3): kh = s - lr - 5
      #pragma unroll
      for (int lr = 0; lr < 8; ++lr) {
        const int kh = s - lr - 5;
        if (kh >= 0 && kh < 3) {
          #pragma unroll
          for (int T = 0; T < 15; ++T) {               // horiz tap, col -> e = dw+T+2
            const float wgt = wv[(T / 3) * 9 + kh * 3 + (T % 3)];
            #pragma unroll
            for (int dw = 0; dw < 4; ++dw)
              acc2[lr % 3][dw] = fmaf(win[dw + T + 2], wgt, acc2[lr % 3][dw]);
          }
          #pragma unroll
          for (int kw = 0; kw < 3; ++kw) {
            const float wgt = wv[18 + kh * 3 + kw];
            #pragma unroll
            for (int dw = 0; dw < 4; ++dw)
              acc3[lr % 3][dw] = fmaf(win[dw + kw + 7], wgt, acc3[lr % 3][dw]);
          }
        }
      }
    }

    // fold1 (lora1 complete at r = h+8, i.e. s = lr+14) — before fold2:
    // at the same s they share stash slot (s-14 == s-7 mod 7), read-then-write.
    if (s >= 14) {
      const int lr = s - 14;
      if (PASS2) {
        const int hh = h0 + lr;
        const float4 xv = *reinterpret_cast<const float4*>(in + ibase + hh * HW + w0);
        float4 o;
        o.x = fmaf(A1, acc1[lr][0], stash[lr % 7][0] + K_ + xv.x);
        o.y = fmaf(A1, acc1[lr][1], stash[lr % 7][1] + K_ + xv.y);
        o.z = fmaf(A1, acc1[lr][2], stash[lr % 7][2] + K_ + xv.z);
        o.w = fmaf(A1, acc1[lr][3], stash[lr % 7][3] + K_ + xv.w);
        *reinterpret_cast<float4*>(out + (size_t)(b * CIN + c) * IMG + hh * HW + w0) = o;
      } else {
        #pragma unroll
        for (int dw = 0; dw < 4; ++dw) {
          const float v = acc1[lr][dw];
          s1 += v; q1 = fmaf(v, v, q1);
        }
      }
    }
    // fold2 (lora2/small complete at r = h+1, i.e. s = lr+7)
    if (s >= 7 && s <= 14) {
      const int lr = s - 7;
      #pragma unroll
      for (int dw = 0; dw < 4; ++dw) {
        const float v2 = acc2[lr % 3][dw], v3 = acc3[lr % 3][dw];
        if (PASS2) {
          stash[lr % 7][dw] = fmaf(A2, v2, A3 * v3);
        } else {
          s2 += v2; q2 = fmaf(v2, v2, q2);
          s3 += v3; q3 = fmaf(v3, v3, q3);
        }
        acc2[lr % 3][dw] = 0.f;
        acc3[lr % 3][dw] = 0.f;
      }
    }
  }

  if (!PASS2) {
    __shared__ float red[7][6];
    #pragma unroll
    for (int off = 32; off > 0; off >>= 1) {
      s1 += __shfl_down(s1, off); q1 += __shfl_down(q1, off);
      s2 += __shfl_down(s2, off); q2 += __shfl_down(q2, off);
      s3 += __shfl_down(s3, off); q3 += __shfl_down(q3, off);
    }
    const int lane = tid & 63, wid = tid >> 6;
    if (lane == 0) {
      red[wid][0] = s1; red[wid][1] = q1; red[wid][2] = s2;
      red[wid][3] = q2; red[wid][4] = s3; red[wid][5] = q3;
    }
    __syncthreads();
    if (tid < 6) {
      float t = 0;
      #pragma unroll
      for (int w = 0; w < 7; ++w) t += red[w][tid];
      partial[(c * 7 + rb) * 6 + tid] = t;
    }
  }
}

extern "C" __global__ void sw_prep(const float* __restrict__ w1, const float* __restrict__ w2,
                                   float* __restrict__ wsum) {
  int i = blockIdx.x * 256 + threadIdx.x;
  if (i < 8820) wsum[i] = w1[i] + w2[i];
}

extern "C" __global__ void sw_reduce(
    const float* __restrict__ partial,
    const float* __restrict__ g1, const float* __restrict__ b1,
    const float* __restrict__ g2, const float* __restrict__ b2,
    const float* __restrict__ g3, const float* __restrict__ b3,
    float* __restrict__ stats2) {
  const int c = blockIdx.x;
  const int tid = threadIdx.x;
  __shared__ float sm[6];
  if (tid < 6) {
    float s = 0;
    #pragma unroll
    for (int rb = 0; rb < 7; ++rb) s += partial[(c * 7 + rb) * 6 + tid];
    sm[tid] = s;
  }
  __syncthreads();
  if (tid == 0) {
    const float N = 100352.f;
    float m1 = sm[0] / N, v1 = sm[1] / N - m1 * m1;
    float m2 = sm[2] / N, v2 = sm[3] / N - m2 * m2;
    float m3 = sm[4] / N, v3 = sm[5] / N - m3 * m3;
    float A1 = g1[c] * rsqrtf(v1 + 1e-5f);
    float A2 = g2[c] * rsqrtf(v2 + 1e-5f);
    float A3 = g3[c] * rsqrtf(v3 + 1e-5f);
    float K = b1[c] + b2[c] + b3[c] - m1 * A1 - m2 * A2 - m3 * A3;
    stats2[c * 4 + 0] = A1; stats2[c * 4 + 1] = A2;
    stats2[c * 4 + 2] = A3; stats2[c * 4 + 3] = K;
  }
}

extern "C" void kernel_launch(void* const* d_in, const int* in_sizes, int n_in,
                              void* d_out, int out_size, void* d_ws, size_t ws_size,
                              hipStream_t stream) {
  const float* in  = (const float*)d_in[0];
  const float* w1  = (const float*)d_in[1];
  const float* w2  = (const float*)d_in[2];
  const float* g1  = (const float*)d_in[3];
  const float* b1  = (const float*)d_in[4];
  const float* g2  = (const float*)d_in[5];
  const float* b2  = (const float*)d_in[6];
  const float* g3  = (const float*)d_in[7];
  const float* b3  = (const float*)d_in[8];
  const int* ghost_idx = (const int*)d_in[9];
  const int* rep_idx   = (const int*)d_in[10];
  float* out = (float*)d_out;
  float* ws  = (float*)d_ws;

  float* wsum    = ws;          // 8820 floats
  float* stats2  = ws + 8832;   // 784 floats
  float* partial = ws + 9728;   // 1372*6 floats

  sw_prep<<<35, 256, 0, stream>>>(w1, w2, wsum);
  sw_conv<false><<<NCONVBLK, 448, 0, stream>>>(in, rep_idx, ghost_idx, wsum, stats2, partial, out);
  sw_reduce<<<196, 64, 0, stream>>>(partial, g1, b1, g2, b2, g3, b3, stats2);
  sw_conv<true><<<NCONVBLK + NGHOSTBLK, 448, 0, stream>>>(in, rep_idx, ghost_idx, wsum, stats2, partial, out);
}